// Round 6
// baseline (286.219 us; speedup 1.0000x reference)
//
#include <hip/hip_runtime.h>
#include <cmath>

// PSNR + 3D-SSIM, pred/gt (N=4, C=16->D, H=512, W=512) f32.
// R6: FULL FUSION, no intermediate array. Block = (n, 16x32 px tile); loops
//     d=0..15: stage p,q halo (26x42) -> {S,D,S2,D2} f32 LDS; H-blur -> LDS
//     tmp; W-blur -> regs; D-blur accumulate into 16 per-dout accs (64 VGPR,
//     static idx) via clamp-folded 16x16 weight matrix in LDS (broadcast).
//     Next-slice global loads prefetched into regs across barriers.
//     SSIM + PSNR fused; ws = 32 B of accumulators only.

#define NB 4
#define DD 16
#define HH 512
#define WW 512
#define SLICE (HH * WW)
#define VOL (DD * SLICE)
#define C1F 0.0001f
#define C2F 0.0009f

#define TH 16          // tile rows
#define TW 32          // tile cols
#define SH 26          // staged rows  (TH+10)
#define SW 42          // staged cols  (TW+10)
#define ST4 43         // float4 row stride (pad)
#define NTHR 512
#define NIT 3          // ceil(SH*SW / NTHR) = ceil(1092/512)

struct GW { float g[11]; };

__device__ inline float block_sum512(float v) {
#pragma unroll
  for (int o = 32; o > 0; o >>= 1) v += __shfl_down(v, o, 64);
  __shared__ float r[8];
  if ((threadIdx.x & 63) == 0) r[threadIdx.x >> 6] = v;
  __syncthreads();
  float out = 0.f;
  if (threadIdx.x == 0) {
#pragma unroll
    for (int i = 0; i < 8; ++i) out += r[i];
  }
  __syncthreads();
  return out;
}

__global__ void zero_acc_k(float* acc) {
  if (threadIdx.x < 8) acc[threadIdx.x] = 0.f;
}

__global__ __launch_bounds__(NTHR, 3) void fused_k(
    const float* __restrict__ pred, const float* __restrict__ gt,
    float* __restrict__ acc, GW gw) {
  __shared__ float4 sd4[SH * ST4];   // staged {S,D,S2,D2}   17.9 KB
  __shared__ float4 tmp[TH * ST4];   // H-blurred fields     11.0 KB
  __shared__ float WL[DD * DD];      // D-blur weights        1.0 KB
  int b = blockIdx.x;
  int tile = b & 511;                // 32 h-tiles x 16 w-tiles
  int n = b >> 9;
  int th0 = (tile >> 4) * TH;
  int tw0 = (tile & 15) * TW;
  int t = threadIdx.x;

  // clamp-folded D-blur weights: WL[dout*16+d] = sum_{k: clamp(dout+k-5)==d} g[k]
  if (t < DD * DD) {
    int dout = t >> 4, d = t & 15;
    float w = 0.f;
#pragma unroll
    for (int k = 0; k < 11; ++k) {
      int j = dout + k - 5; j = j < 0 ? 0 : (j > 15 ? 15 : j);
      if (j == d) w += gw.g[k];
    }
    WL[t] = w;
  }

  // stage-item metadata (NIT items per thread)
  int goff[NIT], laddr[NIT];
  bool iv[NIT], own[NIT];
#pragma unroll
  for (int it = 0; it < NIT; ++it) {
    int i = t + it * NTHR;
    iv[it] = i < SH * SW;
    int ii = iv[it] ? i : 0;
    int y = ii / SW, x = ii - y * SW;
    int gy = th0 + y - 5; gy = gy < 0 ? 0 : (gy > HH - 1 ? HH - 1 : gy);
    int gx = tw0 + x - 5; gx = gx < 0 ? 0 : (gx > WW - 1 ? WW - 1 : gx);
    goff[it] = gy * WW + gx;
    laddr[it] = y * ST4 + x;
    own[it] = (y >= 5) && (y < 5 + TH) && (x >= 5) && (x < 5 + TW);
  }
  const float* pbase = pred + (size_t)n * VOL;
  const float* qbase = gt + (size_t)n * VOL;

  // prefetch slice 0
  float pv[NIT], qv[NIT];
#pragma unroll
  for (int it = 0; it < NIT; ++it) {
    pv[it] = iv[it] ? pbase[goff[it]] : 0.f;
    qv[it] = iv[it] ? qbase[goff[it]] : 0.f;
  }

  float psnr = 0.f;
  float accs[DD][4];
#pragma unroll
  for (int j = 0; j < DD; ++j) {
    accs[j][0] = 0.f; accs[j][1] = 0.f; accs[j][2] = 0.f; accs[j][3] = 0.f;
  }
  __syncthreads();   // WL visible

  int wy = t >> 5, wx = t & 31;   // this thread's output px in tile
#pragma unroll 1
  for (int d = 0; d < DD; ++d) {
    // stage-write slice d from prefetched regs
#pragma unroll
    for (int it = 0; it < NIT; ++it) {
      if (iv[it]) {
        float S = pv[it] + qv[it], Dm = pv[it] - qv[it];
        sd4[laddr[it]] = make_float4(S, Dm, S * S, Dm * Dm);
        if (own[it]) psnr = fmaf(Dm, Dm, psnr);
      }
    }
    __syncthreads();
    // prefetch slice d+1 (consumed next iteration; hides latency under H/W)
    if (d < DD - 1) {
      const float* pd = pbase + (size_t)(d + 1) * SLICE;
      const float* qd = qbase + (size_t)(d + 1) * SLICE;
#pragma unroll
      for (int it = 0; it < NIT; ++it) {
        if (iv[it]) { pv[it] = pd[goff[it]]; qv[it] = qd[goff[it]]; }
      }
    }
    // H-blur: 16 rows x 42 cols items
    for (int i = t; i < TH * SW; i += NTHR) {
      int r = i / SW, c = i - r * SW;
      float a0 = 0.f, a1 = 0.f, a2 = 0.f, a3 = 0.f;
#pragma unroll
      for (int k = 0; k < 11; ++k) {
        float4 v = sd4[(r + k) * ST4 + c];
        float g = gw.g[k];
        a0 = fmaf(g, v.x, a0);
        a1 = fmaf(g, v.y, a1);
        a2 = fmaf(g, v.z, a2);
        a3 = fmaf(g, v.w, a3);
      }
      tmp[r * ST4 + c] = make_float4(a0, a1, a2, a3);
    }
    __syncthreads();
    // W-blur at (wy, wx) + D-blur accumulate
    float h0 = 0.f, h1 = 0.f, h2 = 0.f, h3 = 0.f;
#pragma unroll
    for (int k = 0; k < 11; ++k) {
      float4 v = tmp[wy * ST4 + wx + k];
      float g = gw.g[k];
      h0 = fmaf(g, v.x, h0);
      h1 = fmaf(g, v.y, h1);
      h2 = fmaf(g, v.z, h2);
      h3 = fmaf(g, v.w, h3);
    }
    const float* wl = WL + d;
#pragma unroll
    for (int dout = 0; dout < DD; ++dout) {
      float w = wl[dout * DD];   // broadcast LDS read
      accs[dout][0] = fmaf(w, h0, accs[dout][0]);
      accs[dout][1] = fmaf(w, h1, accs[dout][1]);
      accs[dout][2] = fmaf(w, h2, accs[dout][2]);
      accs[dout][3] = fmaf(w, h3, accs[dout][3]);
    }
    __syncthreads();   // protect sd4/tmp for next slice
  }

  // SSIM over the 16 douts of this px
  float ssum = 0.f;
#pragma unroll
  for (int j = 0; j < DD; ++j) {
    float Sb = accs[j][0], Db = accs[j][1], B1 = accs[j][2], B2 = accs[j][3];
    float SS = Sb * Sb, DDm = Db * Db;
    float m12_2 = (SS - DDm) * 0.5f;     // 2*mu1*mu2
    float msq   = (SS + DDm) * 0.5f;     // mu1^2 + mu2^2
    float Epq   = (B1 - B2) * 0.25f;     // E[pq]
    float Esum  = (B1 + B2) * 0.5f;      // E[p^2+q^2]
    float sig12_2 = 2.f * Epq - m12_2;   // 2*sigma12
    float svar    = Esum - msq;          // sigma1^2 + sigma2^2
    float num = (m12_2 + C1F) * (sig12_2 + C2F);
    float den = (msq + C1F) * (svar + C2F);
    ssum += num / den;
  }
  float bs = block_sum512(ssum);
  if (t == 0) atomicAdd(&acc[4 + n], bs);
  float bp = block_sum512(psnr);
  if (t == 0) atomicAdd(&acc[n], bp);
}

__global__ void final_k(const float* __restrict__ acc, float* __restrict__ out) {
  if (threadIdx.x == 0 && blockIdx.x == 0) {
    double psnr = 0.0, ssim = 0.0;
    for (int n = 0; n < NB; ++n) {
      double mse = (double)acc[n] / (double)VOL;
      psnr += 10.0 * log10(1.0 / mse);
      ssim += (double)acc[4 + n] / (double)VOL;
    }
    out[0] = (float)psnr;
    out[1] = (float)ssim;
    out[2] = (float)NB;
  }
}

extern "C" void kernel_launch(void* const* d_in, const int* in_sizes, int n_in,
                              void* d_out, int out_size, void* d_ws, size_t ws_size,
                              hipStream_t stream) {
  const float* pred = (const float*)d_in[0];
  const float* gt = (const float*)d_in[1];
  float* acc = (float*)d_ws;    // 8 floats
  GW gw;
  double tt[11], s = 0.0;
  for (int i = 0; i < 11; ++i) {
    double x = i - 5;
    tt[i] = exp(-(x * x) / 4.5);
    s += tt[i];
  }
  for (int i = 0; i < 11; ++i) gw.g[i] = (float)(tt[i] / s);

  zero_acc_k<<<1, 64, 0, stream>>>(acc);
  fused_k<<<NB * 512, NTHR, 0, stream>>>(pred, gt, acc, gw);
  final_k<<<1, 1, 0, stream>>>(acc, (float*)d_out);
}